// Round 6
// baseline (1735.029 us; speedup 1.0000x reference)
//
#include <hip/hip_runtime.h>
#include <hip/hip_bf16.h>

typedef unsigned short u16;
typedef unsigned int u32;
typedef unsigned long long u64;
typedef __attribute__((ext_vector_type(8))) short short8;
typedef __attribute__((ext_vector_type(4))) float floatx4;

#define I_DIM 256
#define H_DIM 1024
#define B_DIM 64
#define T_DIM 256
#define C_DIM 60
#define NWG   128
#define UPW   8      // hidden units per WG
#define BSTR  20     // pacc row stride (dwords): 16B-aligned, conflict-benign

// LDS layout (bytes)
#define LDS_W_OFF    0        // 2*40*4*16 frags * 16B = 81920
#define LDS_BIAS_OFF 81920    // 32*4 = 128
#define LDS_PACC_OFF 82048    // 2 bufs * 128 rows * 20 dw * 4B = 20480
#define LDS_TOTAL    102528

// workspace layout (bytes)
#define WS_XSWZ   0u          // T*B*I bf16 = 8388608
#define WS_HSWZ   8388608u    // 256 slots * 64*1024 bf16 = 33554432 (never reused)
#define WS_HLAST  41943040u   // 64*1024 f32 = 262144

#define LSBM 0x0001000100010001ull

__device__ __forceinline__ u16 f2bf(float f) {
    u32 u = __float_as_uint(f);
    u32 r = (u + 0x7fffu + ((u >> 16) & 1u)) >> 16;
    return (u16)r;
}
__device__ __forceinline__ float fsig(float x) { return 1.0f / (1.0f + __expf(-x)); }
__device__ __forceinline__ float ftanh(float x) { return 2.0f * fsig(2.0f * x) - 1.0f; }

union hfrag { short8 s; u64 q[2]; };

// ---------------------------------------------------------------------------
// Pre-swizzle inputs [B][T][I] fp32 -> xswz[t] bf16 in MFMA-A-fragment layout:
// 16B unit index (per t): ((mt*8 + s)*4 + q)*16 + m  holds A[b=mt*16+m][k=s*32+q*8 .. +7]
// ---------------------------------------------------------------------------
extern "C" __global__ void prep_x(const float* __restrict__ in, u16* __restrict__ xswz) {
    int o = blockIdx.x * 256 + threadIdx.x;           // octet index, 524288 total
    int m = o & 15, q = (o >> 4) & 3, s = (o >> 6) & 7, mt = (o >> 9) & 3, t = o >> 11;
    int b = mt * 16 + m, k = s * 32 + q * 8;
    const float* src = in + ((size_t)(b * T_DIM + t)) * I_DIM + k;
    float4 v0 = *(const float4*)src;
    float4 v1 = *(const float4*)(src + 4);
    short8 val;
    val[0] = (short)f2bf(v0.x); val[1] = (short)f2bf(v0.y);
    val[2] = (short)f2bf(v0.z); val[3] = (short)f2bf(v0.w);
    val[4] = (short)f2bf(v1.x); val[5] = (short)f2bf(v1.y);
    val[6] = (short)f2bf(v1.z); val[7] = (short)f2bf(v1.w);
    *(short8*)(xswz + (size_t)o * 8) = val;
}

// ---------------------------------------------------------------------------
// Persistent LSTM scan (r15): r14's 4-way batch-pipeline multiplexing with
// a DEEPER PREFETCH (distance 2, 4-buffer ring) and ONE raw barrier per slot
// (pacc double-buffered). r14 diagnosis: slots were load-RTT-bound -- cur's
// A-frags were issued only 1 slot (~1.4us) before the tag-check consumed all
// 10, so every slot opened with a vmcnt stall. Now slot p issues loads for
// slot p+2 (~2.8us of flight), while the publish->prefetch gap stays a safe
// 2 slots (stores long visible; repair path stays cold). Pointwise balanced
// across all 4 waves (lane<32). Single barrier per slot: write pacc[p&1] ->
// lgkmcnt(0)+s_barrier -> read pacc[p&1]; read(p) < barrier(p+1) <
// write(p+2) makes the double buffer race-free. Publish stays ack-free
// (in-band per-u16 tags, tag=(t%13)+1, never 0=poison; throttled agent-scope
// repair); slot-per-step keeps stale L2 hits structurally impossible.
// ---------------------------------------------------------------------------
extern "C" __global__ void __launch_bounds__(256, 1) lstm_scan(
    const u16* __restrict__ xswz, u16* hswz,
    const float* __restrict__ Wih, const float* __restrict__ Whh,
    const float* __restrict__ bih, const float* __restrict__ bhh,
    float* hlast)
{
    extern __shared__ char lds[];
    u16*   Wlds = (u16*)(lds + LDS_W_OFF);
    float* bias = (float*)(lds + LDS_BIAS_OFF);
    float* pacc = (float*)(lds + LDS_PACC_OFF);

    const int j    = blockIdx.x;
    const int tid  = threadIdx.x;
    const int lane = tid & 63;
    const int w    = tid >> 6;

    // ---- stage W slice into LDS, bf16, B-swizzled:
    // unit wu = ((nt*40 + sg)*4 + q)*16 + nn  holds W[r(nt,nn)][sg*32+q*8 .. +7]
    for (int i = 0; i < 20; ++i) {
        int wu = tid + i * 256;
        int nn = wu & 15, q = (wu >> 4) & 3, rest = wu >> 6;
        int sg = rest % 40, nt = rest / 40;
        int n = nt * 16 + nn;
        int g = n >> 3, uu = n & 7;
        int r = g * H_DIM + j * UPW + uu;
        int kb = sg * 32 + q * 8;
        const float* src = (kb < I_DIM) ? (Wih + (size_t)r * I_DIM + kb)
                                        : (Whh + (size_t)r * H_DIM + (kb - I_DIM));
        short8 val;
        #pragma unroll
        for (int e = 0; e < 8; ++e) val[e] = (short)f2bf(src[e]);
        *(short8*)(Wlds + (size_t)wu * 8) = val;
    }
    if (tid < 32) {
        int n = tid, g = n >> 3, uu = n & 7;
        int r = g * H_DIM + j * UPW + uu;
        bias[n] = bih[r] + bhh[r];
    }
    __syncthreads();   // last fenced barrier in the kernel

    const int m16 = lane & 15, q4 = lane >> 4;
    const int item  = w * 32 + (lane & 31);   // pointwise item (lane<32): 128 items
    const int pw_pm = item >> 3;              // batch-in-16
    const int pw_uu = item & 7;               // hidden unit within WG's 8
    float creg[4] = {0.0f, 0.0f, 0.0f, 0.0f}; // c state, one per pipeline

    hfrag buf[4][10];

    // ---- prologue: load (t=0, p=0) and (t=0, p=1); slot 0 = h_0 = 0
    #pragma unroll
    for (int pp = 0; pp < 2; ++pp)
        #pragma unroll
        for (int ss = 0; ss < 10; ++ss) {
            int sg = w * 10 + ss;
            const u16* src = (sg < 8)
                ? xswz + (size_t)(((pp * 8 + sg) * 4 + q4) * 16 + m16) * 8
                : hswz + (size_t)(((pp * 32 + (sg - 8)) * 4 + q4) * 16 + m16) * 8;
            buf[pp][ss].s = *(const short8*)src;
        }

    for (int t = 0; t < T_DIM; ++t) {
        const u16* xbase = xswz + (size_t)t * (B_DIM * I_DIM);
        const u16* hbase = hswz + (size_t)t * (B_DIM * H_DIM);   // fresh slot
        u16*       hnext = hswz + (size_t)(t + 1) * (B_DIM * H_DIM);
        const int  En    = (t % 13) + 1;          // tag nibble, never 0
        const u64  Eq    = (u64)(En & 1) | ((u64)((En >> 1) & 1) << 16)
                         | ((u64)((En >> 2) & 1) << 32) | ((u64)((En >> 3) & 1) << 48);
        const int  Ep    = ((t + 1) % 13) + 1;

        #pragma unroll
        for (int p = 0; p < 4; ++p) {
            hfrag (&cur)[10] = buf[p];

            // ---- 1) prefetch slot p+2's A-frags (distance 2): target
            // pipeline pp2=(p+2)&3, superstep t (p<2) or t+1 (p>=2). The
            // target h was published 2 slots ago -- visible; loads get
            // 2 slots (~2 slots of machinery) of flight before use.
            if (!(t == T_DIM - 1 && p >= 2)) {
                const int pp2 = (p + 2) & 3;
                const u16* txb = (p >= 2) ? xbase + B_DIM * I_DIM : xbase;
                const u16* thb = (p >= 2) ? hbase + B_DIM * H_DIM : hbase;
                hfrag (&nb)[10] = buf[pp2];
                #pragma unroll
                for (int ss = 0; ss < 10; ++ss) {
                    int sg = w * 10 + ss;
                    const u16* src = (sg < 8)
                        ? txb + (size_t)(((pp2 * 8 + sg) * 4 + q4) * 16 + m16) * 8
                        : thb + (size_t)(((pp2 * 32 + (sg - 8)) * 4 + q4) * 16 + m16) * 8;
                    nb[ss].s = *(const short8*)src;
                }
            }

            // ---- 2) validate cur's h-frag tags; throttled agent repair
            if (t > 0) {
                u32 mk = 0;
                #pragma unroll
                for (int ss = 0; ss < 10; ++ss)
                    if (w * 10 + ss >= 8 &&
                        ((((cur[ss].q[0] ^ Eq) | (cur[ss].q[1] ^ Eq)) & LSBM) != 0))
                        mk |= 1u << ss;
                int rounds = 0;
                while (__any(mk != 0)) {
                    ++rounds;
                    #pragma unroll
                    for (int ss = 0; ss < 10; ++ss) {
                        int sg = w * 10 + ss;
                        if (sg >= 8 && ((mk >> ss) & 1)) {
                            const u64* pp = (const u64*)hbase
                                + (size_t)(((p * 32 + (sg - 8)) * 4 + q4) * 16 + m16) * 2;
                            cur[ss].q[0] = __hip_atomic_load(pp,     __ATOMIC_RELAXED, __HIP_MEMORY_SCOPE_AGENT);
                            cur[ss].q[1] = __hip_atomic_load(pp + 1, __ATOMIC_RELAXED, __HIP_MEMORY_SCOPE_AGENT);
                        }
                    }
                    #pragma unroll
                    for (int ss = 0; ss < 10; ++ss)
                        if (((mk >> ss) & 1) &&
                            ((((cur[ss].q[0] ^ Eq) | (cur[ss].q[1] ^ Eq)) & LSBM) == 0))
                            mk &= ~(1u << ss);
                    if (__any(mk != 0)) {
                        if (rounds < 4) __builtin_amdgcn_s_sleep(4);
                        else            __builtin_amdgcn_s_sleep(16);
                    }
                }
            }

            // ---- 3) MFMA: 20 per wave (K-split: sg = w*10+ss), M-tile = p
            floatx4 acc[2];
            acc[0] = (floatx4){0.f, 0.f, 0.f, 0.f};
            acc[1] = (floatx4){0.f, 0.f, 0.f, 0.f};
            #pragma unroll
            for (int ss = 0; ss < 10; ++ss) {
                int sg = w * 10 + ss;
                #pragma unroll
                for (int nt = 0; nt < 2; ++nt) {
                    short8 bv = *(const short8*)(Wlds
                        + (size_t)(((nt * 40 + sg) * 4 + q4) * 16 + m16) * 8);
                    acc[nt] = __builtin_amdgcn_mfma_f32_16x16x32_bf16(
                        cur[ss].s, bv, acc[nt], 0, 0, 0);
                }
            }

            // ---- 4) K-partials to pacc[p&1] (transposed): row w*32+n, col b16
            float* pc = pacc + (p & 1) * (128 * BSTR);
            #pragma unroll
            for (int nt = 0; nt < 2; ++nt)
                *(floatx4*)(pc + (w * 32 + nt * 16 + m16) * BSTR + q4 * 4) = acc[nt];
            // single raw barrier per slot: LDS drained, vmem stays in flight
            asm volatile("s_waitcnt lgkmcnt(0)" ::: "memory");
            __builtin_amdgcn_s_barrier();
            asm volatile("" ::: "memory");

            // ---- 5) pointwise (all 4 waves, lane<32): reduce 4 wave-
            // partials, gates, c/h update; direct tagged 2B publish
            if (lane < 32) {
                float s[4];
                #pragma unroll
                for (int g = 0; g < 4; ++g) {
                    float v = bias[g * 8 + pw_uu];
                    #pragma unroll
                    for (int ww = 0; ww < 4; ++ww)
                        v += pc[(ww * 32 + g * 8 + pw_uu) * BSTR + pw_pm];
                    s[g] = v;
                }
                float ig = fsig(s[0]), fg = fsig(s[1]), gg = ftanh(s[2]), og = fsig(s[3]);
                float c = fg * creg[p] + ig * gg;
                creg[p] = c;
                float h = og * ftanh(c);
                if (t == T_DIM - 1) {
                    hlast[(size_t)(p * 16 + pw_pm) * H_DIM + j * UPW + pw_uu] = h;
                } else {
                    u16 hb16 = (u16)((f2bf(h) & 0xFFFEu) | ((u32)(Ep >> (pw_uu & 3)) & 1u));
                    // unit octet ((p*32 + (j>>2))*4 + (j&3))*16 + pm, elem uu
                    u16* dst = hnext
                        + (size_t)((p * 32 + (j >> 2)) * 4 + (j & 3)) * 128 + item;
                    __hip_atomic_store(dst, hb16, __ATOMIC_RELAXED,
                                       __HIP_MEMORY_SCOPE_AGENT);
                }
            }
            // no second barrier: pacc is double-buffered; read(p) precedes
            // barrier(p+1) precedes write(p+2) on the same buffer
            asm volatile("" ::: "memory");
        }
    }
}

// ---------------------------------------------------------------------------
// FC + log_softmax: one wave per batch row. logits[b][c] = h.fc_w[c] + fc_b[c]
// ---------------------------------------------------------------------------
extern "C" __global__ void fc_logsoftmax(const float* __restrict__ hlast,
                                         const float* __restrict__ fcw,
                                         const float* __restrict__ fcb,
                                         float* __restrict__ out)
{
    int b = blockIdx.x, c = threadIdx.x;  // 64 threads, 1 wave
    float acc = 0.0f;
    if (c < C_DIM) {
        const float* wr = fcw + (size_t)c * H_DIM;
        const float* hr = hlast + (size_t)b * H_DIM;
        for (int k = 0; k < H_DIM; k += 4) {
            float4 hv = *(const float4*)(hr + k);
            float4 wv = *(const float4*)(wr + k);
            acc += hv.x * wv.x + hv.y * wv.y + hv.z * wv.z + hv.w * wv.w;
        }
        acc += fcb[c];
    }
    float logit = (c < C_DIM) ? acc : -1e30f;
    float mx = logit;
    #pragma unroll
    for (int off = 32; off; off >>= 1) mx = fmaxf(mx, __shfl_xor(mx, off));
    float e = (c < C_DIM) ? expf(logit - mx) : 0.0f;
    float sum = e;
    #pragma unroll
    for (int off = 32; off; off >>= 1) sum += __shfl_xor(sum, off);
    if (c < C_DIM) out[b * C_DIM + c] = logit - mx - logf(sum);
}

extern "C" void kernel_launch(void* const* d_in, const int* in_sizes, int n_in,
                              void* d_out, int out_size, void* d_ws, size_t ws_size,
                              hipStream_t stream)
{
    const float* inputs = (const float*)d_in[0];
    const float* Wih    = (const float*)d_in[1];
    const float* Whh    = (const float*)d_in[2];
    const float* bih    = (const float*)d_in[3];
    const float* bhh    = (const float*)d_in[4];
    const float* fcw    = (const float*)d_in[5];
    const float* fcb    = (const float*)d_in[6];
    float* out = (float*)d_out;

    char* ws = (char*)d_ws;
    u16*   xswz  = (u16*)(ws + WS_XSWZ);
    u16*   hswz  = (u16*)(ws + WS_HSWZ);
    float* hlast = (float*)(ws + WS_HLAST);

    // slot 0 = h_0 = 0 (t=0 skips tag check). Slots t>=1 keep harness poison
    // 0xAA whose tag lsb is 0 -> never validates before the producer's store.
    hipMemsetAsync(hswz, 0, B_DIM * H_DIM * sizeof(u16), stream);

    prep_x<<<2048, 256, 0, stream>>>(inputs, xswz);

    (void)hipFuncSetAttribute((const void*)lstm_scan,
                              hipFuncAttributeMaxDynamicSharedMemorySize, LDS_TOTAL);
    lstm_scan<<<NWG, 256, LDS_TOTAL, stream>>>(xswz, hswz, Wih, Whh, bih, bhh, hlast);
    fc_logsoftmax<<<B_DIM, 64, 0, stream>>>(hlast, fcw, fcb, out);
}

// Round 7
// 926.347 us; speedup vs baseline: 1.8730x; 1.8730x over previous
//
#include <hip/hip_runtime.h>
#include <hip/hip_bf16.h>

typedef unsigned short u16;
typedef unsigned int u32;
typedef unsigned long long u64;
typedef __attribute__((ext_vector_type(8))) short short8;
typedef __attribute__((ext_vector_type(4))) float floatx4;

#define I_DIM 256
#define H_DIM 1024
#define B_DIM 64
#define T_DIM 256
#define C_DIM 60
#define NWG   128
#define UPW   8      // hidden units per WG
#define BSTR  20     // pacc row stride (dwords): 16B-aligned, conflict-free pointwise
#define PACE  5      // post-publish visibility sleep, units of s_sleep(8) (~0.25us)

// LDS layout (bytes)
#define LDS_W_OFF    0        // 2*40*4*16 frags * 16B = 81920
#define LDS_BIAS_OFF 81920    // 32*4 = 128
#define LDS_PACC_OFF 82048    // 4 streams * 2 bufs * 64 rows * 20 dw * 4B = 40960
#define LDS_FLAG_OFF 123008   // 4 ints
#define LDS_TOTAL    123040

// workspace layout (bytes)
#define WS_XSWZ   0u          // T*B*I bf16 = 8388608
#define WS_HSWZ   8388608u    // 256 slots * 64*1024 bf16 = 33554432 (never reused)
#define WS_HLAST  41943040u   // 64*1024 f32 = 262144

#define LSBM 0x0001000100010001ull

__device__ __forceinline__ u16 f2bf(float f) {
    u32 u = __float_as_uint(f);
    u32 r = (u + 0x7fffu + ((u >> 16) & 1u)) >> 16;
    return (u16)r;
}
__device__ __forceinline__ float fsig(float x) { return 1.0f / (1.0f + __expf(-x)); }
__device__ __forceinline__ float ftanh(float x) { return 2.0f * fsig(2.0f * x) - 1.0f; }

union hfrag { short8 s; u64 q[2]; };

// ---------------------------------------------------------------------------
// Pre-swizzle inputs [B][T][I] fp32 -> xswz[t] bf16 in MFMA-A-fragment layout:
// 16B unit index (per t): ((mt*8 + s)*4 + q)*16 + m  holds A[b=mt*16+m][k=s*32+q*8 .. +7]
// ---------------------------------------------------------------------------
extern "C" __global__ void prep_x(const float* __restrict__ in, u16* __restrict__ xswz) {
    int o = blockIdx.x * 256 + threadIdx.x;           // octet index, 524288 total
    int m = o & 15, q = (o >> 4) & 3, s = (o >> 6) & 7, mt = (o >> 9) & 3, t = o >> 11;
    int b = mt * 16 + m, k = s * 32 + q * 8;
    const float* src = in + ((size_t)(b * T_DIM + t)) * I_DIM + k;
    float4 v0 = *(const float4*)src;
    float4 v1 = *(const float4*)(src + 4);
    short8 val;
    val[0] = (short)f2bf(v0.x); val[1] = (short)f2bf(v0.y);
    val[2] = (short)f2bf(v0.z); val[3] = (short)f2bf(v0.w);
    val[4] = (short)f2bf(v1.x); val[5] = (short)f2bf(v1.y);
    val[6] = (short)f2bf(v1.z); val[7] = (short)f2bf(v1.w);
    *(short8*)(xswz + (size_t)o * 8) = val;
}

// ---------------------------------------------------------------------------
// Persistent LSTM scan (r16): CO-RESIDENT INDEPENDENT STREAMS (TLP fix).
// Diagnosis r9-r15: every scheme ran 1 wave/SIMD (Occupancy 6%), so the
// ~83% per-slot stall (visibility RTT, vmcnt, barrier skew) was fully
// exposed -- sync-protocol changes all converged to ~1400us. r16 buys TLP:
// 512-thread WGs = 8 waves = 4 INDEPENDENT 2-wave streams per CU, one
// stream per batch-pipeline (16 batches, full K). Waves 2s,2s+1 map to
// different SIMDs, so each SIMD hosts 2 waves of 2 DIFFERENT streams: when
// one stream stalls/sleeps, the other issues. Per stream per step:
//   4 x-MFMA (pre-tag) -> tag-check h frags (in-band per-u16 tags,
//   tag=(t%13)+1, never 0=poison; throttled agent repair) -> 16 h-MFMA ->
//   pacc[t&1] (stream-private dbuf) -> LDS-atomic sub-barrier (monotonic,
//   2 waves -- NO WG-wide s_barrier in loop, streams never couple) ->
//   pointwise (128 items on 128 lanes, c in regs) -> tagged 2B publish ->
//   issue x loads(t+1) -> sleep PACE (~1us visibility; FREE now: co-streams
//   use the SIMD -- fixes why r13 pacing was worthless) -> issue h loads.
// Slot-per-step hswz keeps stale L2 hits structurally impossible.
// ---------------------------------------------------------------------------
extern "C" __global__ void __launch_bounds__(512, 2) lstm_scan(
    const u16* __restrict__ xswz, u16* hswz,
    const float* __restrict__ Wih, const float* __restrict__ Whh,
    const float* __restrict__ bih, const float* __restrict__ bhh,
    float* hlast)
{
    extern __shared__ char lds[];
    u16*   Wlds = (u16*)(lds + LDS_W_OFF);
    float* bias = (float*)(lds + LDS_BIAS_OFF);
    float* pacc = (float*)(lds + LDS_PACC_OFF);
    int*   sbf  = (int*)(lds + LDS_FLAG_OFF);

    const int j    = blockIdx.x;
    const int tid  = threadIdx.x;
    const int lane = tid & 63;
    const int w    = tid >> 6;
    const int s    = w >> 1;      // stream = pipeline 0..3
    const int ws   = w & 1;       // wave within stream

    // ---- stage W slice into LDS, bf16, B-swizzled:
    // unit wu = ((nt*40 + sg)*4 + q)*16 + nn  holds W[r(nt,nn)][sg*32+q*8 .. +7]
    for (int i = 0; i < 10; ++i) {
        int wu = tid + i * 512;
        int nn = wu & 15, q = (wu >> 4) & 3, rest = wu >> 6;
        int sg = rest % 40, nt = rest / 40;
        int n = nt * 16 + nn;
        int g = n >> 3, uu = n & 7;
        int r = g * H_DIM + j * UPW + uu;
        int kb = sg * 32 + q * 8;
        const float* src = (kb < I_DIM) ? (Wih + (size_t)r * I_DIM + kb)
                                        : (Whh + (size_t)r * H_DIM + (kb - I_DIM));
        short8 val;
        #pragma unroll
        for (int e = 0; e < 8; ++e) val[e] = (short)f2bf(src[e]);
        *(short8*)(Wlds + (size_t)wu * 8) = val;
    }
    if (tid < 32) {
        int n = tid, g = n >> 3, uu = n & 7;
        int r = g * H_DIM + j * UPW + uu;
        bias[n] = bih[r] + bhh[r];
    }
    if (tid < 4) sbf[tid] = 0;
    __syncthreads();   // last WG-wide barrier in the kernel

    const int m16 = lane & 15, q4 = lane >> 4;
    const int sl    = ws * 64 + lane;   // 0..127 within stream
    const int pw_pm = sl >> 3;          // batch-in-16
    const int pw_uu = sl & 7;           // hidden unit within WG's 8
    float creg = 0.0f;                  // c state for this lane's item
    float* pacc_s = pacc + s * (2 * 64 * BSTR);
    int*   flag   = sbf + s;

    // A-frags: ss 0..3 = x (sg = ws*4+ss), ss 4..19 = h (sgh = ws*16+ss-4)
    hfrag a[20];

    // ---- prologue: loads for t=0 (slot 0 = h_0 = 0, no tag check at t=0)
    #pragma unroll
    for (int ss = 0; ss < 4; ++ss) {
        int sg = ws * 4 + ss;
        a[ss].s = *(const short8*)(xswz
            + (size_t)(((s * 8 + sg) * 4 + q4) * 16 + m16) * 8);
    }
    #pragma unroll
    for (int ss = 4; ss < 20; ++ss) {
        int sgh = ws * 16 + (ss - 4);
        a[ss].s = *(const short8*)(hswz
            + (size_t)(((s * 32 + sgh) * 4 + q4) * 16 + m16) * 8);
    }

    for (int t = 0; t < T_DIM; ++t) {
        const u16* hbase = hswz + (size_t)t * (B_DIM * H_DIM);   // fresh slot
        u16*       hnext = hswz + (size_t)(t + 1) * (B_DIM * H_DIM);
        const u16* xnext = xswz + (size_t)(t + 1) * (B_DIM * I_DIM);
        const int  En    = (t % 13) + 1;          // tag nibble, never 0
        const u64  Eq    = (u64)(En & 1) | ((u64)((En >> 1) & 1) << 16)
                         | ((u64)((En >> 2) & 1) << 32) | ((u64)((En >> 3) & 1) << 48);
        const int  Ep    = ((t + 1) % 13) + 1;

        // ---- x part: 8 MFMAs while h loads (still in flight) arrive
        floatx4 acc[2];
        acc[0] = (floatx4){0.f, 0.f, 0.f, 0.f};
        acc[1] = (floatx4){0.f, 0.f, 0.f, 0.f};
        #pragma unroll
        for (int ss = 0; ss < 4; ++ss) {
            int sg = ws * 4 + ss;
            #pragma unroll
            for (int nt = 0; nt < 2; ++nt) {
                short8 bv = *(const short8*)(Wlds
                    + (size_t)(((nt * 40 + sg) * 4 + q4) * 16 + m16) * 8);
                acc[nt] = __builtin_amdgcn_mfma_f32_16x16x32_bf16(
                    a[ss].s, bv, acc[nt], 0, 0, 0);
            }
        }

        // ---- validate h-frag tags; throttled agent-scope repair
        if (t > 0) {
            u32 mk = 0;
            #pragma unroll
            for (int ss = 4; ss < 20; ++ss)
                if ((((a[ss].q[0] ^ Eq) | (a[ss].q[1] ^ Eq)) & LSBM) != 0)
                    mk |= 1u << ss;
            int rounds = 0;
            while (__any(mk != 0)) {
                ++rounds;
                #pragma unroll
                for (int ss = 4; ss < 20; ++ss)
                    if ((mk >> ss) & 1) {
                        int sgh = ws * 16 + (ss - 4);
                        const u64* pp = (const u64*)hbase
                            + (size_t)(((s * 32 + sgh) * 4 + q4) * 16 + m16) * 2;
                        a[ss].q[0] = __hip_atomic_load(pp,     __ATOMIC_RELAXED, __HIP_MEMORY_SCOPE_AGENT);
                        a[ss].q[1] = __hip_atomic_load(pp + 1, __ATOMIC_RELAXED, __HIP_MEMORY_SCOPE_AGENT);
                    }
                #pragma unroll
                for (int ss = 4; ss < 20; ++ss)
                    if (((mk >> ss) & 1) &&
                        ((((a[ss].q[0] ^ Eq) | (a[ss].q[1] ^ Eq)) & LSBM) == 0))
                        mk &= ~(1u << ss);
                if (__any(mk != 0)) {
                    if (rounds < 4) __builtin_amdgcn_s_sleep(4);
                    else            __builtin_amdgcn_s_sleep(16);
                }
            }
        }

        // ---- h part: 32 MFMAs (16 h-sg x 2 ntiles)
        #pragma unroll
        for (int ss = 4; ss < 20; ++ss) {
            int sg = 8 + ws * 16 + (ss - 4);
            #pragma unroll
            for (int nt = 0; nt < 2; ++nt) {
                short8 bv = *(const short8*)(Wlds
                    + (size_t)(((nt * 40 + sg) * 4 + q4) * 16 + m16) * 8);
                acc[nt] = __builtin_amdgcn_mfma_f32_16x16x32_bf16(
                    a[ss].s, bv, acc[nt], 0, 0, 0);
            }
        }

        // ---- K-partials to stream-private pacc[t&1] (transposed)
        float* pc = pacc_s + (t & 1) * (64 * BSTR);
        #pragma unroll
        for (int nt = 0; nt < 2; ++nt)
            *(floatx4*)(pc + (ws * 32 + nt * 16 + m16) * BSTR + q4 * 4) = acc[nt];

        // ---- stream sub-barrier (monotonic LDS counter, 2 waves)
        asm volatile("s_waitcnt lgkmcnt(0)" ::: "memory");
        if (lane == 0)
            __hip_atomic_fetch_add(flag, 1, __ATOMIC_RELAXED,
                                   __HIP_MEMORY_SCOPE_WORKGROUP);
        {
            const int tgt = 2 * (t + 1);
            while (__hip_atomic_load(flag, __ATOMIC_RELAXED,
                                     __HIP_MEMORY_SCOPE_WORKGROUP) < tgt)
                __builtin_amdgcn_s_sleep(1);
        }
        asm volatile("" ::: "memory");

        // ---- pointwise: reduce 2 wave-partials, gates, c/h; tagged publish
        {
            float sv[4];
            #pragma unroll
            for (int g = 0; g < 4; ++g) {
                sv[g] = bias[g * 8 + pw_uu]
                      + pc[(g * 8 + pw_uu) * BSTR + pw_pm]
                      + pc[(32 + g * 8 + pw_uu) * BSTR + pw_pm];
            }
            float ig = fsig(sv[0]), fg = fsig(sv[1]), gg = ftanh(sv[2]), og = fsig(sv[3]);
            float c = fg * creg + ig * gg;
            creg = c;
            float h = og * ftanh(c);
            if (t == T_DIM - 1) {
                hlast[(size_t)(s * 16 + pw_pm) * H_DIM + j * UPW + pw_uu] = h;
            } else {
                u16 hb16 = (u16)((f2bf(h) & 0xFFFEu) | ((u32)(Ep >> (pw_uu & 3)) & 1u));
                // unit octet ((s*32 + (j>>2))*4 + (j&3))*16 + pm, elem uu
                u16* dst = hnext
                    + (size_t)((s * 32 + (j >> 2)) * 4 + (j & 3)) * 128 + sl;
                __hip_atomic_store(dst, hb16, __ATOMIC_RELAXED,
                                   __HIP_MEMORY_SCOPE_AGENT);
            }
        }
        asm volatile("" ::: "memory");

        // ---- issue next step's loads: x now (tag-free), h after the
        // visibility sleep (sleep is free: co-streams use the SIMD)
        if (t + 1 < T_DIM) {
            #pragma unroll
            for (int ss = 0; ss < 4; ++ss) {
                int sg = ws * 4 + ss;
                a[ss].s = *(const short8*)(xnext
                    + (size_t)(((s * 8 + sg) * 4 + q4) * 16 + m16) * 8);
            }
            for (int p = 0; p < PACE; ++p) __builtin_amdgcn_s_sleep(8);
            #pragma unroll
            for (int ss = 4; ss < 20; ++ss) {
                int sgh = ws * 16 + (ss - 4);
                a[ss].s = *(const short8*)(hnext
                    + (size_t)(((s * 32 + sgh) * 4 + q4) * 16 + m16) * 8);
            }
        }
    }
}

// ---------------------------------------------------------------------------
// FC + log_softmax: one wave per batch row. logits[b][c] = h.fc_w[c] + fc_b[c]
// ---------------------------------------------------------------------------
extern "C" __global__ void fc_logsoftmax(const float* __restrict__ hlast,
                                         const float* __restrict__ fcw,
                                         const float* __restrict__ fcb,
                                         float* __restrict__ out)
{
    int b = blockIdx.x, c = threadIdx.x;  // 64 threads, 1 wave
    float acc = 0.0f;
    if (c < C_DIM) {
        const float* wr = fcw + (size_t)c * H_DIM;
        const float* hr = hlast + (size_t)b * H_DIM;
        for (int k = 0; k < H_DIM; k += 4) {
            float4 hv = *(const float4*)(hr + k);
            float4 wv = *(const float4*)(wr + k);
            acc += hv.x * wv.x + hv.y * wv.y + hv.z * wv.z + hv.w * wv.w;
        }
        acc += fcb[c];
    }
    float logit = (c < C_DIM) ? acc : -1e30f;
    float mx = logit;
    #pragma unroll
    for (int off = 32; off; off >>= 1) mx = fmaxf(mx, __shfl_xor(mx, off));
    float e = (c < C_DIM) ? expf(logit - mx) : 0.0f;
    float sum = e;
    #pragma unroll
    for (int off = 32; off; off >>= 1) sum += __shfl_xor(sum, off);
    if (c < C_DIM) out[b * C_DIM + c] = logit - mx - logf(sum);
}

extern "C" void kernel_launch(void* const* d_in, const int* in_sizes, int n_in,
                              void* d_out, int out_size, void* d_ws, size_t ws_size,
                              hipStream_t stream)
{
    const float* inputs = (const float*)d_in[0];
    const float* Wih    = (const float*)d_in[1];
    const float* Whh    = (const float*)d_in[2];
    const float* bih    = (const float*)d_in[3];
    const float* bhh    = (const float*)d_in[4];
    const float* fcw    = (const float*)d_in[5];
    const float* fcb    = (const float*)d_in[6];
    float* out = (float*)d_out;

    char* ws = (char*)d_ws;
    u16*   xswz  = (u16*)(ws + WS_XSWZ);
    u16*   hswz  = (u16*)(ws + WS_HSWZ);
    float* hlast = (float*)(ws + WS_HLAST);

    // slot 0 = h_0 = 0 (t=0 skips tag check). Slots t>=1 keep harness poison
    // 0xAA whose tag lsb is 0 -> never validates before the producer's store.
    hipMemsetAsync(hswz, 0, B_DIM * H_DIM * sizeof(u16), stream);

    prep_x<<<2048, 256, 0, stream>>>(inputs, xswz);

    (void)hipFuncSetAttribute((const void*)lstm_scan,
                              hipFuncAttributeMaxDynamicSharedMemorySize, LDS_TOTAL);
    lstm_scan<<<NWG, 512, LDS_TOTAL, stream>>>(xswz, hswz, Wih, Whh, bih, bhh, hlast);
    fc_logsoftmax<<<B_DIM, 64, 0, stream>>>(hlast, fcw, fcb, out);
}